// Round 1
// baseline (243.314 us; speedup 1.0000x reference)
//
#include <hip/hip_runtime.h>
#include <hip/hip_bf16.h>
#include <stdint.h>

// MoE (E=16, D=1024, H=2048, K=2, T=2048), routed bf16-MFMA implementation.
// Pipeline: cvt(w1,w2,inp -> bf16 in ws) ; route (sort pair-ids by expert) ;
// GEMM1 (gather x rows, fused bias+gelu, h bf16 in routed order) ;
// GEMM2 (contiguous h rows, fused bias+gate_score, scatter y by pair id) ;
// combine (out[t] = y[2t] + y[2t+1]).  No atomics in the math path.

#define E_ 16
#define D_ 1024
#define H_ 2048
#define K_ 2
#define T_ 2048
#define NP_ (T_ * K_)   // 4096 token-expert pairs

using short8 = __attribute__((ext_vector_type(8))) short;
using f32x4  = __attribute__((ext_vector_type(4))) float;

__device__ __forceinline__ unsigned short f2bf(float f) {
  union { float f; unsigned u; } x; x.f = f;
  unsigned r = x.u + 0x7fffu + ((x.u >> 16) & 1u);   // RNE
  return (unsigned short)(r >> 16);
}

// gelu(tanh approx) = x * sigmoid(1.595769...*(x + 0.044715 x^3))
__device__ __forceinline__ float gelu_f(float x) {
  float u = 1.5957691216057308f * (x + 0.044715f * x * x * x);
  return x / (1.f + __expf(-u));
}

__global__ void cvt_kernel(const float* __restrict__ src,
                           unsigned short* __restrict__ dst, int n4) {
  int stride = gridDim.x * blockDim.x;
  for (int i = blockIdx.x * blockDim.x + threadIdx.x; i < n4; i += stride) {
    float4 v = reinterpret_cast<const float4*>(src)[i];
    ushort4 o = make_ushort4(f2bf(v.x), f2bf(v.y), f2bf(v.z), f2bf(v.w));
    reinterpret_cast<ushort4*>(dst)[i] = o;
  }
}

__global__ void route_kernel(const int* __restrict__ gidx,
                             int* __restrict__ rows,
                             int* __restrict__ offsets) {
  __shared__ int cnt[E_], cur[E_];
  int tid = threadIdx.x;
  if (tid < E_) cnt[tid] = 0;
  __syncthreads();
  for (int p = tid; p < NP_; p += blockDim.x) atomicAdd(&cnt[gidx[p]], 1);
  __syncthreads();
  if (tid == 0) {
    int acc = 0;
    for (int e = 0; e < E_; ++e) { offsets[e] = acc; cur[e] = acc; acc += cnt[e]; }
    offsets[E_] = acc;
  }
  __syncthreads();
  for (int p = tid; p < NP_; p += blockDim.x) {
    int e = gidx[p];
    int pos = atomicAdd(&cur[e], 1);
    rows[pos] = p;
  }
}

#define GLOAD16(g, l)                                                        \
  __builtin_amdgcn_global_load_lds(                                          \
      (const __attribute__((address_space(1))) unsigned int*)(const void*)(g), \
      (__attribute__((address_space(3))) unsigned int*)(void*)(l), 16, 0, 0)

// NT GEMM, m97 structure: 128x128 tile, BK=32, 4 waves (each 64x64 = 4x4
// mfma_f32_16x16x32_bf16 fragments), global_load_lds width-16 staging.
template<bool IS1>
__global__ __launch_bounds__(256, 2)
void moe_gemm(const unsigned short* __restrict__ A0,   // xb (IS1) or h
              const unsigned short* __restrict__ W,    // w1b or w2b
              const float* __restrict__ bias,          // b1 or b2  [E][NN]
              const int* __restrict__ rows,
              const int* __restrict__ offsets,
              const float* __restrict__ score,         // [T*K]
              unsigned short* __restrict__ Hout,       // h (IS1)
              float* __restrict__ Yout)                // y (!IS1)
{
  constexpr int BM = 128, BN = 128, BK = 32;
  constexpr int KD = IS1 ? D_ : H_;   // contraction dim
  constexpr int NN = IS1 ? H_ : D_;   // output cols

  const int e   = blockIdx.z;
  const int off = offsets[e];
  const int ne  = offsets[e + 1] - off;
  const int m0  = blockIdx.y * BM;
  if (m0 >= ne) return;
  const int n0 = blockIdx.x * BN;

  __shared__ unsigned short As[BM][BK];
  __shared__ unsigned short Bs[BN][BK];
  __shared__ int rowsrc[BM];
  __shared__ int rowdst[BM];

  const int tid  = threadIdx.x;
  const int lane = tid & 63;
  const int wid  = tid >> 6;

  if (tid < BM) {
    int i = m0 + tid;
    bool v = i < ne;
    int s = off + (v ? i : 0);        // clamped routed slot
    if (IS1) {
      int p = rows[s];
      rowsrc[tid] = p >> 1;           // token id (K_=2)
      rowdst[tid] = v ? s : -1;       // h row (routed order)
    } else {
      rowsrc[tid] = s;                // h row
      rowdst[tid] = v ? rows[s] : -1; // pair id for scatter + score
    }
  }
  __syncthreads();

  // Staging: per wave 2 x 1KB chunks for A and for B (lane = 16B).
  const int r0 = wid * 32 + (lane >> 2);
  const int r1 = r0 + 16;
  const int c8 = (lane & 3) * 8;
  const unsigned short* Wb = W + (size_t)e * NN * KD;
  const unsigned short* srcA0 = A0 + (size_t)rowsrc[r0] * KD + c8;
  const unsigned short* srcA1 = A0 + (size_t)rowsrc[r1] * KD + c8;
  const unsigned short* srcB0 = Wb + (size_t)(n0 + r0) * KD + c8;
  const unsigned short* srcB1 = Wb + (size_t)(n0 + r1) * KD + c8;
  unsigned short* ldsA0 = &As[wid * 32][0];
  unsigned short* ldsA1 = &As[wid * 32 + 16][0];
  unsigned short* ldsB0 = &Bs[wid * 32][0];
  unsigned short* ldsB1 = &Bs[wid * 32 + 16][0];

  const int wr = wid >> 1, wc = wid & 1;
  const int fr = lane & 15, fh = lane >> 4;

  f32x4 acc[4][4] = {};

  for (int kk = 0; kk < KD; kk += BK) {
    GLOAD16(srcA0 + kk, ldsA0);
    GLOAD16(srcA1 + kk, ldsA1);
    GLOAD16(srcB0 + kk, ldsB0);
    GLOAD16(srcB1 + kk, ldsB1);
    __syncthreads();
    short8 af[4], bfr[4];
#pragma unroll
    for (int mi = 0; mi < 4; ++mi)
      af[mi] = *reinterpret_cast<const short8*>(&As[wr * 64 + mi * 16 + fr][fh * 8]);
#pragma unroll
    for (int ni = 0; ni < 4; ++ni)
      bfr[ni] = *reinterpret_cast<const short8*>(&Bs[wc * 64 + ni * 16 + fr][fh * 8]);
#pragma unroll
    for (int mi = 0; mi < 4; ++mi)
#pragma unroll
      for (int ni = 0; ni < 4; ++ni)
        acc[mi][ni] = __builtin_amdgcn_mfma_f32_16x16x32_bf16(af[mi], bfr[ni],
                                                              acc[mi][ni], 0, 0, 0);
    __syncthreads();
  }

  // Epilogue. C/D map: row = (lane>>4)*4 + j, col = lane&15 (m89-verified).
  const float* biasE = bias + (size_t)e * NN + n0;
#pragma unroll
  for (int mi = 0; mi < 4; ++mi) {
#pragma unroll
    for (int j = 0; j < 4; ++j) {
      int rt  = wr * 64 + mi * 16 + fh * 4 + j;
      int dst = rowdst[rt];
      if (dst < 0) continue;
      float sc = IS1 ? 0.f : score[dst];
#pragma unroll
      for (int ni = 0; ni < 4; ++ni) {
        int col = wc * 64 + ni * 16 + fr;
        float v = acc[mi][ni][j] + biasE[col];
        if (IS1) {
          Hout[(size_t)dst * H_ + n0 + col] = f2bf(gelu_f(v));
        } else {
          Yout[(size_t)dst * D_ + n0 + col] = v * sc;
        }
      }
    }
  }
}

__global__ void combine_kernel(const float* __restrict__ y,
                               float* __restrict__ out) {
  const int DQ = D_ / 4;
  int i = blockIdx.x * blockDim.x + threadIdx.x;   // [0, T_*D_/4)
  int t = i / DQ, d = i % DQ;
  const float4* y4 = reinterpret_cast<const float4*>(y);
  float4 a = y4[(size_t)(2 * t) * DQ + d];
  float4 b = y4[(size_t)(2 * t + 1) * DQ + d];
  reinterpret_cast<float4*>(out)[i] =
      make_float4(a.x + b.x, a.y + b.y, a.z + b.z, a.w + b.w);
}

extern "C" void kernel_launch(void* const* d_in, const int* in_sizes, int n_in,
                              void* d_out, int out_size, void* d_ws, size_t ws_size,
                              hipStream_t stream) {
  const float* inp    = (const float*)d_in[0];
  const int*   gidx   = (const int*)d_in[1];
  const float* gscore = (const float*)d_in[2];
  const float* w1     = (const float*)d_in[3];
  const float* b1     = (const float*)d_in[4];
  const float* w2     = (const float*)d_in[5];
  const float* b2     = (const float*)d_in[6];
  float* out = (float*)d_out;

  char* ws = (char*)d_ws;
  size_t o = 0;
  auto alloc = [&](size_t bytes) {
    void* p = ws + o;
    o = (o + bytes + 255) & ~(size_t)255;
    return p;
  };
  unsigned short* w1b  = (unsigned short*)alloc((size_t)E_ * H_ * D_ * 2);
  unsigned short* w2b  = (unsigned short*)alloc((size_t)E_ * D_ * H_ * 2);
  unsigned short* xb   = (unsigned short*)alloc((size_t)T_ * D_ * 2);
  unsigned short* hbuf = (unsigned short*)alloc((size_t)NP_ * H_ * 2);
  float*          ybuf = (float*)alloc((size_t)NP_ * D_ * 4);
  int*            rows = (int*)alloc(NP_ * 4);
  int*         offsets = (int*)alloc((E_ + 1) * 4);

  cvt_kernel<<<dim3(2048), dim3(256), 0, stream>>>(w1, w1b, E_ * H_ * D_ / 4);
  cvt_kernel<<<dim3(2048), dim3(256), 0, stream>>>(w2, w2b, E_ * D_ * H_ / 4);
  cvt_kernel<<<dim3(64),   dim3(256), 0, stream>>>(inp, xb, T_ * D_ / 4);
  route_kernel<<<dim3(1), dim3(256), 0, stream>>>(gidx, rows, offsets);

  moe_gemm<true><<<dim3(H_ / 128, 32, E_), dim3(256), 0, stream>>>(
      xb, w1b, b1, rows, offsets, gscore, hbuf, (float*)nullptr);
  moe_gemm<false><<<dim3(D_ / 128, 32, E_), dim3(256), 0, stream>>>(
      hbuf, w2b, b2, rows, offsets, gscore, (unsigned short*)nullptr, ybuf);

  combine_kernel<<<dim3(T_ * D_ / 4 / 256), dim3(256), 0, stream>>>(ybuf, out);
}

// Round 2
// 241.311 us; speedup vs baseline: 1.0083x; 1.0083x over previous
//
#include <hip/hip_runtime.h>
#include <hip/hip_bf16.h>
#include <stdint.h>

// MoE (E=16, D=1024, H=2048, K=2, T=2048), routed bf16-MFMA.
// R2: fused f32-weight conversion inside the GEMM (no separate w cvt passes),
// 2-phase double-buffered K-loop (BK=64, one barrier per K-step), A staged via
// global_load_lds with pre-swizzled source + swizzled read (bank-conflict-free),
// B reg-staged f32->bf16 into a +8-padded LDS tile.

#define E_ 16
#define D_ 1024
#define H_ 2048
#define K_ 2
#define T_ 2048
#define NP_ (T_ * K_)   // 4096 token-expert pairs

using short8 = __attribute__((ext_vector_type(8))) short;
using f32x4  = __attribute__((ext_vector_type(4))) float;

__device__ __forceinline__ unsigned short f2bf(float f) {
  union { float f; unsigned u; } x; x.f = f;
  unsigned r = x.u + 0x7fffu + ((x.u >> 16) & 1u);   // RNE
  return (unsigned short)(r >> 16);
}

__device__ __forceinline__ unsigned short cvt_bf(float f) {
  __hip_bfloat16 h = __float2bfloat16(f);
  union { __hip_bfloat16 h; unsigned short u; } c; c.h = h; return c.u;
}

// gelu(tanh approx) = x * sigmoid(1.595769...*(x + 0.044715 x^3))
__device__ __forceinline__ float gelu_f(float x) {
  float u = 1.5957691216057308f * (x + 0.044715f * x * x * x);
  return x / (1.f + __expf(-u));
}

__global__ void cvt_kernel(const float* __restrict__ src,
                           unsigned short* __restrict__ dst, int n4) {
  int stride = gridDim.x * blockDim.x;
  for (int i = blockIdx.x * blockDim.x + threadIdx.x; i < n4; i += stride) {
    float4 v = reinterpret_cast<const float4*>(src)[i];
    ushort4 o = make_ushort4(f2bf(v.x), f2bf(v.y), f2bf(v.z), f2bf(v.w));
    reinterpret_cast<ushort4*>(dst)[i] = o;
  }
}

__global__ void route_kernel(const int* __restrict__ gidx,
                             int* __restrict__ rows,
                             int* __restrict__ offsets) {
  __shared__ int cnt[E_], cur[E_];
  int tid = threadIdx.x;
  if (tid < E_) cnt[tid] = 0;
  __syncthreads();
  for (int p = tid; p < NP_; p += blockDim.x) atomicAdd(&cnt[gidx[p]], 1);
  __syncthreads();
  if (tid == 0) {
    int acc = 0;
    for (int e = 0; e < E_; ++e) { offsets[e] = acc; cur[e] = acc; acc += cnt[e]; }
    offsets[E_] = acc;
  }
  __syncthreads();
  for (int p = tid; p < NP_; p += blockDim.x) {
    int e = gidx[p];
    int pos = atomicAdd(&cur[e], 1);
    rows[pos] = p;
  }
}

#define GLOAD16(g, l)                                                        \
  __builtin_amdgcn_global_load_lds(                                          \
      (const __attribute__((address_space(1))) unsigned int*)(const void*)(g), \
      (__attribute__((address_space(3))) unsigned int*)(void*)(l), 16, 0, 0)

// NT GEMM: 128x128 tile, BK=64, 4 waves (each 64x64 = 4x4 x 2 k-substeps of
// mfma_f32_16x16x32_bf16). A (bf16) via global_load_lds with source-side XOR
// swizzle; B (f32 weights) reg-staged + converted to bf16 into padded LDS.
template<bool IS1>
__global__ __launch_bounds__(256, 2)
void moe_gemm(const unsigned short* __restrict__ A0,   // xb (IS1) or h
              const float* __restrict__ W,             // w1 or w2 (f32!)
              const float* __restrict__ bias,          // b1 or b2  [E][NN]
              const int* __restrict__ rows,
              const int* __restrict__ offsets,
              const float* __restrict__ score,         // [T*K]
              unsigned short* __restrict__ Hout,       // h (IS1)
              float* __restrict__ Yout)                // y (!IS1)
{
  constexpr int BM = 128, BN = 128, BK = 64;
  constexpr int KD = IS1 ? D_ : H_;   // contraction dim
  constexpr int NN = IS1 ? H_ : D_;   // output cols
  constexpr int NT = KD / BK;         // 16 or 32 (even)

  const int e   = blockIdx.z;
  const int off = offsets[e];
  const int ne  = offsets[e + 1] - off;
  const int m0  = blockIdx.y * BM;
  if (m0 >= ne) return;
  const int n0 = blockIdx.x * BN;

  __shared__ unsigned short As[2][BM][BK];       // slot-swizzled (XOR row&7)
  __shared__ unsigned short Bs[2][BM][BK + 8];   // +8 pad kills bank conflicts
  __shared__ int rowsrc[BM];
  __shared__ int rowdst[BM];

  const int tid  = threadIdx.x;
  const int lane = tid & 63;
  const int wid  = tid >> 6;

  if (tid < BM) {
    int i = m0 + tid;
    bool v = i < ne;
    int s = off + (v ? i : 0);        // clamped routed slot
    if (IS1) {
      int p = rows[s];
      rowsrc[tid] = p >> 1;           // token id (K_=2)
      rowdst[tid] = v ? s : -1;       // h row (routed order)
    } else {
      rowsrc[tid] = s;                // h row
      rowdst[tid] = v ? rows[s] : -1; // pair id for scatter + score
    }
  }
  __syncthreads();

  // A staging: per wave 4 x global_load_lds(16B) chunks of 8 rows each.
  // LDS dest is linear (base + lane*16); the SOURCE col-slot is pre-XOR'd so
  // reads can be de-swizzled (m173/m201 pattern; slot' = slot ^ (row&7)).
  const int arow  = lane >> 3;                 // row within 8-row chunk (=row&7)
  const int aslot = (lane & 7) ^ arow;         // pre-swizzled global slot
  const unsigned short* gA[4];
#pragma unroll
  for (int i = 0; i < 4; ++i)
    gA[i] = A0 + (size_t)rowsrc[wid * 32 + i * 8 + arow] * KD + aslot * 8;

  // B staging: thread t handles row t>>1, 32-col half (t&1). 8 float4 loads.
  const int brow = tid >> 1, bh = tid & 1;
  const float* gB = W + (size_t)e * NN * KD + (size_t)(n0 + brow) * KD + bh * 32;

  const int wr = wid >> 1, wc = wid & 1;
  const int fr = lane & 15, fh = lane >> 4;

  f32x4 acc[4][4] = {};
  float4 breg[8];

  auto stageA = [&](int buf, int kk) {
#pragma unroll
    for (int i = 0; i < 4; ++i)
      GLOAD16(gA[i] + kk, &As[buf][wid * 32 + i * 8][0]);
  };
  auto loadB = [&](int kk) {
#pragma unroll
    for (int j = 0; j < 8; ++j)
      breg[j] = *reinterpret_cast<const float4*>(gB + kk + j * 4);
  };
  auto writeB = [&](int buf) {
#pragma unroll
    for (int j = 0; j < 4; ++j) {
      short8 v;
#pragma unroll
      for (int q = 0; q < 4; ++q) v[q]     = (short)cvt_bf((&breg[2*j].x)[q]);
#pragma unroll
      for (int q = 0; q < 4; ++q) v[4 + q] = (short)cvt_bf((&breg[2*j+1].x)[q]);
      *reinterpret_cast<short8*>(&Bs[buf][brow][bh * 32 + j * 8]) = v;
    }
  };
  auto compute = [&](int buf) {
    short8 af[4][2], bv[4][2];
#pragma unroll
    for (int mi = 0; mi < 4; ++mi) {
      const int row = wr * 64 + mi * 16 + fr;     // row&7 == fr&7
#pragma unroll
      for (int ks = 0; ks < 2; ++ks) {
        const int slot = (ks * 4 + fh) ^ (fr & 7);
        af[mi][ks] = *reinterpret_cast<const short8*>(&As[buf][row][slot * 8]);
      }
    }
#pragma unroll
    for (int ni = 0; ni < 4; ++ni) {
      const int row = wc * 64 + ni * 16 + fr;
#pragma unroll
      for (int ks = 0; ks < 2; ++ks)
        bv[ni][ks] = *reinterpret_cast<const short8*>(&Bs[buf][row][ks * 32 + fh * 8]);
    }
#pragma unroll
    for (int ks = 0; ks < 2; ++ks)
#pragma unroll
      for (int mi = 0; mi < 4; ++mi)
#pragma unroll
        for (int ni = 0; ni < 4; ++ni)
          acc[mi][ni] = __builtin_amdgcn_mfma_f32_16x16x32_bf16(
              af[mi][ks], bv[ni][ks], acc[mi][ni], 0, 0, 0);
  };

  // Prologue: tile 0 into buf0.
  stageA(0, 0);
  loadB(0);
  writeB(0);
  __syncthreads();

  // 2-phase pipeline, one barrier per K-step; loads of t+1 overlap MFMA of t.
  // NT is even, so buffer indices are compile-time static.
  for (int t = 0; t < NT; t += 2) {
    stageA(1, (t + 1) * BK);      // t+1 always < NT (NT even)
    loadB((t + 1) * BK);
    compute(0);
    writeB(1);                    // waits breg vmcnt; barrier drains gload_lds
    __syncthreads();
    if (t + 2 < NT) { stageA(0, (t + 2) * BK); loadB((t + 2) * BK); }
    compute(1);
    if (t + 2 < NT) writeB(0);
    __syncthreads();
  }

  // Epilogue. C/D map: row = (lane>>4)*4 + j, col = lane&15 (m89-verified).
  const float* biasE = bias + (size_t)e * NN + n0;
#pragma unroll
  for (int mi = 0; mi < 4; ++mi) {
#pragma unroll
    for (int j = 0; j < 4; ++j) {
      int rt  = wr * 64 + mi * 16 + fh * 4 + j;
      int dst = rowdst[rt];
      if (dst < 0) continue;
      float sc = IS1 ? 0.f : score[dst];
#pragma unroll
      for (int ni = 0; ni < 4; ++ni) {
        int col = wc * 64 + ni * 16 + fr;
        float v = acc[mi][ni][j] + biasE[col];
        if (IS1) {
          Hout[(size_t)dst * H_ + n0 + col] = f2bf(gelu_f(v));
        } else {
          Yout[(size_t)dst * D_ + n0 + col] = v * sc;
        }
      }
    }
  }
}

__global__ void combine_kernel(const float* __restrict__ y,
                               float* __restrict__ out) {
  const int DQ = D_ / 4;
  int i = blockIdx.x * blockDim.x + threadIdx.x;   // [0, T_*D_/4)
  int t = i / DQ, d = i % DQ;
  const float4* y4 = reinterpret_cast<const float4*>(y);
  float4 a = y4[(size_t)(2 * t) * DQ + d];
  float4 b = y4[(size_t)(2 * t + 1) * DQ + d];
  reinterpret_cast<float4*>(out)[i] =
      make_float4(a.x + b.x, a.y + b.y, a.z + b.z, a.w + b.w);
}

extern "C" void kernel_launch(void* const* d_in, const int* in_sizes, int n_in,
                              void* d_out, int out_size, void* d_ws, size_t ws_size,
                              hipStream_t stream) {
  const float* inp    = (const float*)d_in[0];
  const int*   gidx   = (const int*)d_in[1];
  const float* gscore = (const float*)d_in[2];
  const float* w1     = (const float*)d_in[3];
  const float* b1     = (const float*)d_in[4];
  const float* w2     = (const float*)d_in[5];
  const float* b2     = (const float*)d_in[6];
  float* out = (float*)d_out;

  char* ws = (char*)d_ws;
  size_t o = 0;
  auto alloc = [&](size_t bytes) {
    void* p = ws + o;
    o = (o + bytes + 255) & ~(size_t)255;
    return p;
  };
  unsigned short* xb   = (unsigned short*)alloc((size_t)T_ * D_ * 2);
  unsigned short* hbuf = (unsigned short*)alloc((size_t)NP_ * H_ * 2);
  float*          ybuf = (float*)alloc((size_t)NP_ * D_ * 4);
  int*            rows = (int*)alloc(NP_ * 4);
  int*         offsets = (int*)alloc((E_ + 1) * 4);

  cvt_kernel<<<dim3(256), dim3(256), 0, stream>>>(inp, xb, T_ * D_ / 4);
  route_kernel<<<dim3(1), dim3(256), 0, stream>>>(gidx, rows, offsets);

  moe_gemm<true><<<dim3(H_ / 128, 32, E_), dim3(256), 0, stream>>>(
      xb, w1, b1, rows, offsets, gscore, hbuf, (float*)nullptr);
  moe_gemm<false><<<dim3(D_ / 128, 32, E_), dim3(256), 0, stream>>>(
      hbuf, w2, b2, rows, offsets, gscore, (unsigned short*)nullptr, ybuf);

  combine_kernel<<<dim3(T_ * D_ / 4 / 256), dim3(256), 0, stream>>>(ybuf, out);
}

// Round 3
// 171.577 us; speedup vs baseline: 1.4181x; 1.4064x over previous
//
#include <hip/hip_runtime.h>
#include <hip/hip_bf16.h>
#include <stdint.h>

// MoE (E=16, D=1024, H=2048, K=2, T=2048), routed bf16-MFMA.
// R3: compact grid via device-built M-tile table (heavy blocks contiguous in
// dispatch order), BN=64 (more blocks), LDS 52KB (3 blocks/CU), fused
// f32->bf16 weight staging (weights read ~once from HBM), 2-phase dbuf loop.

#define E_ 16
#define D_ 1024
#define H_ 2048
#define K_ 2
#define T_ 2048
#define NP_ (T_ * K_)     // 4096 token-expert pairs
#define MTS_ 48           // max M-tiles: sum ceil(ne/128) <= 32+16 = 48

using short8 = __attribute__((ext_vector_type(8))) short;
using f32x4  = __attribute__((ext_vector_type(4))) float;

__device__ __forceinline__ unsigned short f2bf(float f) {
  union { float f; unsigned u; } x; x.f = f;
  unsigned r = x.u + 0x7fffu + ((x.u >> 16) & 1u);   // RNE
  return (unsigned short)(r >> 16);
}

// gelu(tanh approx) = x * sigmoid(1.595769...*(x + 0.044715 x^3))
__device__ __forceinline__ float gelu_f(float x) {
  float u = 1.5957691216057308f * (x + 0.044715f * x * x * x);
  return x / (1.f + __expf(-u));
}

__global__ void cvt_kernel(const float* __restrict__ src,
                           unsigned short* __restrict__ dst, int n4) {
  int stride = gridDim.x * blockDim.x;
  for (int i = blockIdx.x * blockDim.x + threadIdx.x; i < n4; i += stride) {
    float4 v = reinterpret_cast<const float4*>(src)[i];
    ushort4 o = make_ushort4(f2bf(v.x), f2bf(v.y), f2bf(v.z), f2bf(v.w));
    reinterpret_cast<ushort4*>(dst)[i] = o;
  }
}

__global__ void route_kernel(const int* __restrict__ gidx,
                             int* __restrict__ rows,
                             int* __restrict__ offsets,
                             int2* __restrict__ tiles) {
  __shared__ int cnt[E_], cur[E_];
  int tid = threadIdx.x;
  if (tid < E_) cnt[tid] = 0;
  __syncthreads();
  for (int p = tid; p < NP_; p += blockDim.x) atomicAdd(&cnt[gidx[p]], 1);
  __syncthreads();
  if (tid == 0) {
    int acc = 0;
    for (int e = 0; e < E_; ++e) { offsets[e] = acc; cur[e] = acc; acc += cnt[e]; }
    offsets[E_] = acc;
    int k = 0;
    for (int e = 0; e < E_; ++e)
      for (int m = offsets[e]; m < offsets[e] + cnt[e]; m += 128)
        tiles[k++] = make_int2(e, m);
    for (; k < MTS_; ++k) tiles[k] = make_int2(-1, 0);
  }
  __syncthreads();
  for (int p = tid; p < NP_; p += blockDim.x) {
    int e = gidx[p];
    int pos = atomicAdd(&cur[e], 1);
    rows[pos] = p;
  }
}

#define GLOAD16(g, l)                                                        \
  __builtin_amdgcn_global_load_lds(                                          \
      (const __attribute__((address_space(1))) unsigned int*)(const void*)(g), \
      (__attribute__((address_space(3))) unsigned int*)(void*)(l), 16, 0, 0)

// NT GEMM: 128(M)x64(N) tile, BK=64, 4 waves as 2x2 (each 64x32).
// A (bf16) via global_load_lds, source-side XOR swizzle (verified R2).
// B (f32 weights) reg-staged + converted to bf16 into padded LDS.
template<bool IS1>
__global__ __launch_bounds__(256, 3)
void moe_gemm(const unsigned short* __restrict__ A0,   // xb (IS1) or h
              const float* __restrict__ W,             // w1 or w2 (f32)
              const float* __restrict__ bias,          // b1 or b2  [E][NN]
              const int* __restrict__ rows,
              const int* __restrict__ offsets,
              const int2* __restrict__ tiles,
              const float* __restrict__ score,         // [T*K]
              unsigned short* __restrict__ Hout,       // h (IS1)
              float* __restrict__ Yout)                // y (!IS1)
{
  constexpr int BM = 128, BN = 64, BK = 64;
  constexpr int KD = IS1 ? D_ : H_;   // contraction dim
  constexpr int NN = IS1 ? H_ : D_;   // output cols
  constexpr int NT = KD / BK;         // 16 or 32 (even)

  const int2 tile = tiles[blockIdx.y];
  const int e = tile.x;
  if (e < 0) return;
  const int s0   = tile.y;            // absolute routed-slot base of this tile
  const int send = offsets[e + 1];    // end slot for this expert
  const int n0   = blockIdx.x * BN;

  __shared__ unsigned short As[2][BM][BK];       // slot-swizzled (XOR row&7)
  __shared__ unsigned short Bs[2][BN][BK + 8];   // +8 pad (16B, keeps align)
  __shared__ int rowsrc[BM];
  __shared__ int rowdst[BM];

  const int tid  = threadIdx.x;
  const int lane = tid & 63;
  const int wid  = tid >> 6;

  if (tid < BM) {
    int s = s0 + tid;
    bool v = s < send;
    int sc2 = v ? s : s0;             // clamped routed slot
    if (IS1) {
      rowsrc[tid] = rows[sc2] >> 1;   // token id (K_=2)
      rowdst[tid] = v ? s : -1;       // h row (routed order)
    } else {
      rowsrc[tid] = sc2;              // h row
      rowdst[tid] = v ? rows[s] : -1; // pair id for scatter + score
    }
  }
  __syncthreads();

  // A staging: per wave 4 x global_load_lds(16B) chunks of 8 rows each.
  // LDS dest linear; SOURCE col-slot pre-XOR'd (slot' = slot ^ (row&7)).
  const int arow  = lane >> 3;
  const int aslot = (lane & 7) ^ arow;
  const unsigned short* gA[4];
#pragma unroll
  for (int i = 0; i < 4; ++i)
    gA[i] = A0 + (size_t)rowsrc[wid * 32 + i * 8 + arow] * KD + aslot * 8;

  // B staging: thread t -> row t>>2 (0..63), 16-col seg (t&3). 4 float4 loads.
  const int brow = tid >> 2, bseg = tid & 3;
  const float* gB = W + (size_t)e * NN * KD + (size_t)(n0 + brow) * KD + bseg * 16;

  const int wr = wid >> 1, wc = wid & 1;
  const int fr = lane & 15, fh = lane >> 4;

  f32x4 acc[4][2] = {};
  float4 breg[4];

  auto stageA = [&](int buf, int kk) {
#pragma unroll
    for (int i = 0; i < 4; ++i)
      GLOAD16(gA[i] + kk, &As[buf][wid * 32 + i * 8][0]);
  };
  auto loadB = [&](int kk) {
#pragma unroll
    for (int j = 0; j < 4; ++j)
      breg[j] = *reinterpret_cast<const float4*>(gB + kk + j * 4);
  };
  auto writeB = [&](int buf) {
#pragma unroll
    for (int h = 0; h < 2; ++h) {
      short8 v;
#pragma unroll
      for (int q = 0; q < 4; ++q) v[q]     = (short)f2bf((&breg[2*h].x)[q]);
#pragma unroll
      for (int q = 0; q < 4; ++q) v[4 + q] = (short)f2bf((&breg[2*h+1].x)[q]);
      *reinterpret_cast<short8*>(&Bs[buf][brow][bseg * 16 + h * 8]) = v;
    }
  };
  auto compute = [&](int buf) {
    short8 af[4][2], bv[2][2];
#pragma unroll
    for (int mi = 0; mi < 4; ++mi) {
      const int row = wr * 64 + mi * 16 + fr;
#pragma unroll
      for (int ks = 0; ks < 2; ++ks) {
        const int slot = (ks * 4 + fh) ^ (fr & 7);
        af[mi][ks] = *reinterpret_cast<const short8*>(&As[buf][row][slot * 8]);
      }
    }
#pragma unroll
    for (int ni = 0; ni < 2; ++ni) {
      const int row = wc * 32 + ni * 16 + fr;
#pragma unroll
      for (int ks = 0; ks < 2; ++ks)
        bv[ni][ks] = *reinterpret_cast<const short8*>(&Bs[buf][row][ks * 32 + fh * 8]);
    }
#pragma unroll
    for (int ks = 0; ks < 2; ++ks)
#pragma unroll
      for (int mi = 0; mi < 4; ++mi)
#pragma unroll
        for (int ni = 0; ni < 2; ++ni)
          acc[mi][ni] = __builtin_amdgcn_mfma_f32_16x16x32_bf16(
              af[mi][ks], bv[ni][ks], acc[mi][ni], 0, 0, 0);
  };

  // Prologue: tile 0 into buf0.
  loadB(0);
  stageA(0, 0);
  writeB(0);
  __syncthreads();

  // 2-phase pipeline: loads of step t+1 issued before compute of step t.
  for (int t = 0; t < NT; t += 2) {
    loadB((t + 1) * BK);
    stageA(1, (t + 1) * BK);
    compute(0);
    writeB(1);
    __syncthreads();
    if (t + 2 < NT) { loadB((t + 2) * BK); stageA(0, (t + 2) * BK); }
    compute(1);
    if (t + 2 < NT) writeB(0);
    __syncthreads();
  }

  // Epilogue. C/D map: row = (lane>>4)*4 + j, col = lane&15 (m89-verified).
  const float* biasE = bias + (size_t)e * NN + n0;
#pragma unroll
  for (int mi = 0; mi < 4; ++mi) {
#pragma unroll
    for (int j = 0; j < 4; ++j) {
      int rt  = wr * 64 + mi * 16 + fh * 4 + j;
      int dst = rowdst[rt];
      if (dst < 0) continue;
      float sc = IS1 ? 0.f : score[dst];
#pragma unroll
      for (int ni = 0; ni < 2; ++ni) {
        int col = wc * 32 + ni * 16 + fr;
        float v = acc[mi][ni][j] + biasE[col];
        if (IS1) {
          Hout[(size_t)dst * H_ + n0 + col] = f2bf(gelu_f(v));
        } else {
          Yout[(size_t)dst * D_ + n0 + col] = v * sc;
        }
      }
    }
  }
}

__global__ void combine_kernel(const float* __restrict__ y,
                               float* __restrict__ out) {
  const int DQ = D_ / 4;
  int i = blockIdx.x * blockDim.x + threadIdx.x;   // [0, T_*D_/4)
  int t = i / DQ, d = i % DQ;
  const float4* y4 = reinterpret_cast<const float4*>(y);
  float4 a = y4[(size_t)(2 * t) * DQ + d];
  float4 b = y4[(size_t)(2 * t + 1) * DQ + d];
  reinterpret_cast<float4*>(out)[i] =
      make_float4(a.x + b.x, a.y + b.y, a.z + b.z, a.w + b.w);
}

extern "C" void kernel_launch(void* const* d_in, const int* in_sizes, int n_in,
                              void* d_out, int out_size, void* d_ws, size_t ws_size,
                              hipStream_t stream) {
  const float* inp    = (const float*)d_in[0];
  const int*   gidx   = (const int*)d_in[1];
  const float* gscore = (const float*)d_in[2];
  const float* w1     = (const float*)d_in[3];
  const float* b1     = (const float*)d_in[4];
  const float* w2     = (const float*)d_in[5];
  const float* b2     = (const float*)d_in[6];
  float* out = (float*)d_out;

  char* ws = (char*)d_ws;
  size_t o = 0;
  auto alloc = [&](size_t bytes) {
    void* p = ws + o;
    o = (o + bytes + 255) & ~(size_t)255;
    return p;
  };
  unsigned short* xb   = (unsigned short*)alloc((size_t)T_ * D_ * 2);
  unsigned short* hbuf = (unsigned short*)alloc((size_t)NP_ * H_ * 2);
  float*          ybuf = (float*)alloc((size_t)NP_ * D_ * 4);
  int*            rows = (int*)alloc(NP_ * 4);
  int*         offsets = (int*)alloc((E_ + 1) * 4);
  int2*          tiles = (int2*)alloc(MTS_ * 8);

  cvt_kernel<<<dim3(256), dim3(256), 0, stream>>>(inp, xb, T_ * D_ / 4);
  route_kernel<<<dim3(1), dim3(256), 0, stream>>>(gidx, rows, offsets, tiles);

  moe_gemm<true><<<dim3(H_ / 64, MTS_, 1), dim3(256), 0, stream>>>(
      xb, w1, b1, rows, offsets, tiles, gscore, hbuf, (float*)nullptr);
  moe_gemm<false><<<dim3(D_ / 64, MTS_, 1), dim3(256), 0, stream>>>(
      hbuf, w2, b2, rows, offsets, tiles, gscore, (unsigned short*)nullptr, ybuf);

  combine_kernel<<<dim3(T_ * D_ / 4 / 256), dim3(256), 0, stream>>>(ybuf, out);
}

// Round 4
// 157.067 us; speedup vs baseline: 1.5491x; 1.0924x over previous
//
#include <hip/hip_runtime.h>
#include <hip/hip_bf16.h>
#include <stdint.h>

// MoE (E=16, D=1024, H=2048, K=2, T=2048), routed bf16-MFMA.
// R4: counted-vmcnt software pipeline (raw s_barrier, never vmcnt(0) in
// steady state). Per K-step: issue A(t+2) via global_load_lds + B(t+2) via
// reg loads, wait vmcnt(8) -> loads span 2 K-steps. B f32->bf16 converted
// in-reg, ds_written with XOR-slot swizzle (no pad). 128x64x64 tile, 4 waves,
// 49KB LDS -> 3 blocks/CU.

#define E_ 16
#define D_ 1024
#define H_ 2048
#define K_ 2
#define T_ 2048
#define NP_ (T_ * K_)     // 4096 token-expert pairs
#define MTS_ 48           // max M-tiles: sum ceil(ne/128) <= 48

using short8 = __attribute__((ext_vector_type(8))) short;
using f32x4  = __attribute__((ext_vector_type(4))) float;

__device__ __forceinline__ unsigned short f2bf(float f) {
  union { float f; unsigned u; } x; x.f = f;
  unsigned r = x.u + 0x7fffu + ((x.u >> 16) & 1u);   // RNE
  return (unsigned short)(r >> 16);
}

// gelu(tanh approx) = x * sigmoid(1.595769...*(x + 0.044715 x^3))
__device__ __forceinline__ float gelu_f(float x) {
  float u = 1.5957691216057308f * (x + 0.044715f * x * x * x);
  return x / (1.f + __expf(-u));
}

__device__ __forceinline__ void waitv8() {
  asm volatile("s_waitcnt vmcnt(8)" ::: "memory");
  __builtin_amdgcn_sched_barrier(0);
}
__device__ __forceinline__ void waitv0() {
  asm volatile("s_waitcnt vmcnt(0)" ::: "memory");
  __builtin_amdgcn_sched_barrier(0);
}
__device__ __forceinline__ void barrier_only() {
  __builtin_amdgcn_sched_barrier(0);
  __builtin_amdgcn_s_barrier();
  __builtin_amdgcn_sched_barrier(0);
}
__device__ __forceinline__ void lgkm0_barrier() {
  asm volatile("s_waitcnt lgkmcnt(0)" ::: "memory");
  __builtin_amdgcn_sched_barrier(0);
  __builtin_amdgcn_s_barrier();
  __builtin_amdgcn_sched_barrier(0);
}

__global__ void cvt_kernel(const float* __restrict__ src,
                           unsigned short* __restrict__ dst, int n4) {
  int stride = gridDim.x * blockDim.x;
  for (int i = blockIdx.x * blockDim.x + threadIdx.x; i < n4; i += stride) {
    float4 v = reinterpret_cast<const float4*>(src)[i];
    ushort4 o = make_ushort4(f2bf(v.x), f2bf(v.y), f2bf(v.z), f2bf(v.w));
    reinterpret_cast<ushort4*>(dst)[i] = o;
  }
}

__global__ void route_kernel(const int* __restrict__ gidx,
                             int* __restrict__ rows,
                             int* __restrict__ offsets,
                             int2* __restrict__ tiles) {
  __shared__ int cnt[E_], cur[E_];
  int tid = threadIdx.x;
  if (tid < E_) cnt[tid] = 0;
  __syncthreads();
  for (int p = tid; p < NP_; p += blockDim.x) atomicAdd(&cnt[gidx[p]], 1);
  __syncthreads();
  if (tid == 0) {
    int acc = 0;
    for (int e = 0; e < E_; ++e) { offsets[e] = acc; cur[e] = acc; acc += cnt[e]; }
    offsets[E_] = acc;
    int k = 0;
    for (int e = 0; e < E_; ++e)
      for (int m = offsets[e]; m < offsets[e] + cnt[e]; m += 128)
        tiles[k++] = make_int2(e, m);
    for (; k < MTS_; ++k) tiles[k] = make_int2(-1, 0);
  }
  __syncthreads();
  for (int p = tid; p < NP_; p += blockDim.x) {
    int e = gidx[p];
    int pos = atomicAdd(&cur[e], 1);
    rows[pos] = p;
  }
}

#define GLOAD16(g, l)                                                        \
  __builtin_amdgcn_global_load_lds(                                          \
      (const __attribute__((address_space(1))) unsigned int*)(const void*)(g), \
      (__attribute__((address_space(3))) unsigned int*)(void*)(l), 16, 0, 0)

// NT GEMM: 128(M)x64(N) tile, BK=64, 4 waves as 2x2 (each 64x32).
// A (bf16) via global_load_lds, source-side XOR swizzle (verified R2/R3).
// B (f32) reg-staged depth-2, cvt to bf16, ds_write with same XOR swizzle.
template<bool IS1>
__global__ __launch_bounds__(256, 3)
void moe_gemm(const unsigned short* __restrict__ A0,   // xb (IS1) or h
              const float* __restrict__ W,             // w1 or w2 (f32)
              const float* __restrict__ bias,          // b1 or b2  [E][NN]
              const int* __restrict__ rows,
              const int* __restrict__ offsets,
              const int2* __restrict__ tiles,
              const float* __restrict__ score,         // [T*K]
              unsigned short* __restrict__ Hout,       // h (IS1)
              float* __restrict__ Yout)                // y (!IS1)
{
  constexpr int BM = 128, BN = 64, BK = 64;
  constexpr int KD = IS1 ? D_ : H_;   // contraction dim
  constexpr int NN = IS1 ? H_ : D_;   // output cols
  constexpr int NT = KD / BK;         // 16 or 32 (even)

  const int2 tile = tiles[blockIdx.y];
  const int e = tile.x;
  if (e < 0) return;
  const int s0   = tile.y;            // absolute routed-slot base of this tile
  const int send = offsets[e + 1];    // end slot for this expert
  const int n0   = blockIdx.x * BN;

  __shared__ unsigned short As[2][BM][BK];   // XOR-slot swizzled
  __shared__ unsigned short Bs[2][BN][BK];   // XOR-slot swizzled
  __shared__ int rowsrc[BM];
  __shared__ int rowdst[BM];

  const int tid  = threadIdx.x;
  const int lane = tid & 63;
  const int wid  = tid >> 6;

  if (tid < BM) {
    int s = s0 + tid;
    bool v = s < send;
    int sc2 = v ? s : s0;             // clamped routed slot
    if (IS1) {
      rowsrc[tid] = rows[sc2] >> 1;   // token id (K_=2)
      rowdst[tid] = v ? s : -1;       // h row (routed order)
    } else {
      rowsrc[tid] = sc2;              // h row
      rowdst[tid] = v ? rows[s] : -1; // pair id for scatter + score
    }
  }
  __syncthreads();

  // A staging: per wave 4 x global_load_lds(16B), 8 rows each; LDS dest
  // linear, SOURCE slot pre-XOR'd: LDS[row][s] holds global slot s^(row&7).
  const int arow  = lane >> 3;
  const int aslot = (lane & 7) ^ arow;
  const unsigned short* gA[4];
#pragma unroll
  for (int i = 0; i < 4; ++i)
    gA[i] = A0 + (size_t)rowsrc[wid * 32 + i * 8 + arow] * KD + aslot * 8;

  // B staging: thread t -> row t>>2 (0..63), 16-col seg (t&3). 4 float4 loads.
  const int brow = tid >> 2, bseg = tid & 3;
  const float* gB = W + (size_t)e * NN * KD + (size_t)(n0 + brow) * KD + bseg * 16;

  const int wr = wid >> 1, wc = wid & 1;
  const int fr = lane & 15, fh = lane >> 4;

  f32x4 acc[4][2] = {};
  float4 breg0[4], breg1[4];

  auto issueA = [&](int buf, int kk) {
#pragma unroll
    for (int i = 0; i < 4; ++i)
      GLOAD16(gA[i] + kk, &As[buf][wid * 32 + i * 8][0]);
  };
  auto issueB = [&](float4* br, int kk) {
#pragma unroll
    for (int j = 0; j < 4; ++j)
      br[j] = *reinterpret_cast<const float4*>(gB + kk + j * 4);
  };
  auto writeB = [&](int buf, const float4* br) {
#pragma unroll
    for (int j = 0; j < 2; ++j) {
      short8 v;
#pragma unroll
      for (int q = 0; q < 4; ++q) v[q]     = (short)f2bf((&br[2*j].x)[q]);
#pragma unroll
      for (int q = 0; q < 4; ++q) v[4 + q] = (short)f2bf((&br[2*j+1].x)[q]);
      int slot = (bseg * 2 + j) ^ (brow & 7);
      *reinterpret_cast<short8*>(&Bs[buf][brow][slot * 8]) = v;
    }
  };
  auto compute = [&](int buf) {
    short8 af[4][2], bv[2][2];
#pragma unroll
    for (int mi = 0; mi < 4; ++mi) {
      const int row = wr * 64 + mi * 16 + fr;
#pragma unroll
      for (int ks = 0; ks < 2; ++ks) {
        const int slot = (ks * 4 + fh) ^ (row & 7);
        af[mi][ks] = *reinterpret_cast<const short8*>(&As[buf][row][slot * 8]);
      }
    }
#pragma unroll
    for (int ni = 0; ni < 2; ++ni) {
      const int row = wc * 32 + ni * 16 + fr;
#pragma unroll
      for (int ks = 0; ks < 2; ++ks) {
        const int slot = (ks * 4 + fh) ^ (row & 7);
        bv[ni][ks] = *reinterpret_cast<const short8*>(&Bs[buf][row][slot * 8]);
      }
    }
#pragma unroll
    for (int ks = 0; ks < 2; ++ks)
#pragma unroll
      for (int mi = 0; mi < 4; ++mi)
#pragma unroll
        for (int ni = 0; ni < 2; ++ni)
          acc[mi][ni] = __builtin_amdgcn_mfma_f32_16x16x32_bf16(
              af[mi][ks], bv[ni][ks], acc[mi][ni], 0, 0, 0);
  };

  // Prologue: issue tiles 0,1 (16 vmem ops), land tile 0.
  issueA(0, 0);       issueB(breg0, 0);
  issueA(1, BK);      issueB(breg1, BK);
  waitv8();                       // tile-0 ops (first 8) complete
  writeB(0, breg0);
  lgkm0_barrier();                // all waves: tile 0 fully in LDS

  // Steady state: 16 vmem in flight, wait vmcnt(8) -> 2-K-step latency cover.
  for (int t = 0; t < NT; t += 2) {
    // ---- step t (buffers 0) ----
    compute(0);
    barrier_only();               // all waves done reading LDS[0]
    if (t + 2 < NT) {
      issueA(0, (t + 2) * BK); issueB(breg0, (t + 2) * BK);
      waitv8();                   // {t+1} ops complete
    } else {
      waitv0();
    }
    writeB(1, breg1);
    lgkm0_barrier();              // all waves: tile t+1 fully in LDS
    // ---- step t+1 (buffers 1) ----
    compute(1);
    barrier_only();               // all waves done reading LDS[1]
    if (t + 2 < NT) {
      if (t + 3 < NT) { issueA(1, (t + 3) * BK); issueB(breg1, (t + 3) * BK); waitv8(); }
      else            { waitv0(); }
      writeB(0, breg0);
      lgkm0_barrier();            // all waves: tile t+2 fully in LDS
    }
  }

  // Epilogue. C/D map: row = (lane>>4)*4 + j, col = lane&15 (m89-verified).
  const float* biasE = bias + (size_t)e * NN + n0;
#pragma unroll
  for (int mi = 0; mi < 4; ++mi) {
#pragma unroll
    for (int j = 0; j < 4; ++j) {
      int rt  = wr * 64 + mi * 16 + fh * 4 + j;
      int dst = rowdst[rt];
      if (dst < 0) continue;
      float sc = IS1 ? 0.f : score[dst];
#pragma unroll
      for (int ni = 0; ni < 2; ++ni) {
        int col = wc * 32 + ni * 16 + fr;
        float v = acc[mi][ni][j] + biasE[col];
        if (IS1) {
          Hout[(size_t)dst * H_ + n0 + col] = f2bf(gelu_f(v));
        } else {
          Yout[(size_t)dst * D_ + n0 + col] = v * sc;
        }
      }
    }
  }
}

__global__ void combine_kernel(const float* __restrict__ y,
                               float* __restrict__ out) {
  const int DQ = D_ / 4;
  int i = blockIdx.x * blockDim.x + threadIdx.x;   // [0, T_*D_/4)
  int t = i / DQ, d = i % DQ;
  const float4* y4 = reinterpret_cast<const float4*>(y);
  float4 a = y4[(size_t)(2 * t) * DQ + d];
  float4 b = y4[(size_t)(2 * t + 1) * DQ + d];
  reinterpret_cast<float4*>(out)[i] =
      make_float4(a.x + b.x, a.y + b.y, a.z + b.z, a.w + b.w);
}

extern "C" void kernel_launch(void* const* d_in, const int* in_sizes, int n_in,
                              void* d_out, int out_size, void* d_ws, size_t ws_size,
                              hipStream_t stream) {
  const float* inp    = (const float*)d_in[0];
  const int*   gidx   = (const int*)d_in[1];
  const float* gscore = (const float*)d_in[2];
  const float* w1     = (const float*)d_in[3];
  const float* b1     = (const float*)d_in[4];
  const float* w2     = (const float*)d_in[5];
  const float* b2     = (const float*)d_in[6];
  float* out = (float*)d_out;

  char* ws = (char*)d_ws;
  size_t o = 0;
  auto alloc = [&](size_t bytes) {
    void* p = ws + o;
    o = (o + bytes + 255) & ~(size_t)255;
    return p;
  };
  unsigned short* xb   = (unsigned short*)alloc((size_t)T_ * D_ * 2);
  unsigned short* hbuf = (unsigned short*)alloc((size_t)NP_ * H_ * 2);
  float*          ybuf = (float*)alloc((size_t)NP_ * D_ * 4);
  int*            rows = (int*)alloc(NP_ * 4);
  int*         offsets = (int*)alloc((E_ + 1) * 4);
  int2*          tiles = (int2*)alloc(MTS_ * 8);

  cvt_kernel<<<dim3(512), dim3(256), 0, stream>>>(inp, xb, T_ * D_ / 4);
  route_kernel<<<dim3(1), dim3(256), 0, stream>>>(gidx, rows, offsets, tiles);

  moe_gemm<true><<<dim3(H_ / 64, MTS_, 1), dim3(256), 0, stream>>>(
      xb, w1, b1, rows, offsets, tiles, gscore, hbuf, (float*)nullptr);
  moe_gemm<false><<<dim3(D_ / 64, MTS_, 1), dim3(256), 0, stream>>>(
      hbuf, w2, b2, rows, offsets, tiles, gscore, (unsigned short*)nullptr, ybuf);

  combine_kernel<<<dim3(T_ * D_ / 4 / 256), dim3(256), 0, stream>>>(ybuf, out);
}